// Round 1
// baseline (1284.758 us; speedup 1.0000x reference)
//
#include <hip/hip_runtime.h>

// GCN3: 3x (COO spmm -> Linear(64) -> ReLU), segment-mean pool, softmax head.
// Strategy: build CSR per launch (hist/scan/scatter), pull-based spmm fused
// with the dense layer (wave-per-row, lane=dim), run-length pooled reduction.

__global__ void hist_k(const int* __restrict__ rows, int* __restrict__ deg, int E) {
    int e = blockIdx.x * blockDim.x + threadIdx.x;
    if (e < E) atomicAdd(&deg[rows[e]], 1);
}

__global__ void scan1_k(const int* __restrict__ deg, int* __restrict__ rp,
                        int* __restrict__ bsum, int n) {
    __shared__ int s[256];
    int tx = threadIdx.x;
    int i = blockIdx.x * 256 + tx;
    int v = (i < n) ? deg[i] : 0;
    s[tx] = v;
    __syncthreads();
    for (int off = 1; off < 256; off <<= 1) {
        int t = (tx >= off) ? s[tx - off] : 0;
        __syncthreads();
        s[tx] += t;
        __syncthreads();
    }
    if (i < n) rp[i] = s[tx] - v;  // exclusive
    if (tx == 255) bsum[blockIdx.x] = s[255];
}

__global__ void scan2_k(int* bsum, int nb) {
    __shared__ int s[512];
    int tx = threadIdx.x;
    int v = (tx < nb) ? bsum[tx] : 0;
    s[tx] = v;
    __syncthreads();
    for (int off = 1; off < 512; off <<= 1) {
        int t = (tx >= off) ? s[tx - off] : 0;
        __syncthreads();
        s[tx] += t;
        __syncthreads();
    }
    if (tx < nb) bsum[tx] = s[tx] - v;  // exclusive
}

__global__ void scan3_k(const int* __restrict__ bsum, int* __restrict__ rp,
                        int* __restrict__ cursor, int n, int E) {
    int i = blockIdx.x * 256 + threadIdx.x;
    if (i < n) {
        int v = rp[i] + bsum[blockIdx.x];
        rp[i] = v;
        cursor[i] = v;
    }
    if (i == 0) rp[n] = E;
}

__global__ void scatter_k(const int* __restrict__ rows, const int* __restrict__ cols,
                          const float* __restrict__ vals, int* __restrict__ cursor,
                          int2* __restrict__ epack, int E) {
    int e = blockIdx.x * blockDim.x + threadIdx.x;
    if (e < E) {
        int r = rows[e];
        int p = atomicAdd(&cursor[r], 1);
        epack[p] = make_int2(cols[e], __float_as_int(vals[e]));
    }
}

// Layer 1: spmm on [N,5] input, fused with 5x64 Linear + ReLU.
// Wave per row; lanes parallel over edges; 5-dim accumulators; butterfly reduce.
__global__ void layer1_k(const int* __restrict__ rp, const int2* __restrict__ epack,
                         const float* __restrict__ x, const float* __restrict__ W1,
                         const float* __restrict__ b1, float* __restrict__ x1, int n) {
    int lane = threadIdx.x & 63;
    int row = (blockIdx.x * blockDim.x + threadIdx.x) >> 6;
    if (row >= n) return;
    int s = rp[row], e = rp[row + 1];
    float a0 = 0.f, a1 = 0.f, a2 = 0.f, a3 = 0.f, a4 = 0.f;
    for (int j = s + lane; j < e; j += 64) {
        int2 cv = epack[j];
        float v = __int_as_float(cv.y);
        const float* xp = x + (size_t)cv.x * 5;
        a0 = fmaf(v, xp[0], a0);
        a1 = fmaf(v, xp[1], a1);
        a2 = fmaf(v, xp[2], a2);
        a3 = fmaf(v, xp[3], a3);
        a4 = fmaf(v, xp[4], a4);
    }
#pragma unroll
    for (int off = 32; off; off >>= 1) {
        a0 += __shfl_xor(a0, off, 64);
        a1 += __shfl_xor(a1, off, 64);
        a2 += __shfl_xor(a2, off, 64);
        a3 += __shfl_xor(a3, off, 64);
        a4 += __shfl_xor(a4, off, 64);
    }
    float y = b1[lane];
    y = fmaf(a0, W1[lane], y);
    y = fmaf(a1, W1[64 + lane], y);
    y = fmaf(a2, W1[128 + lane], y);
    y = fmaf(a3, W1[192 + lane], y);
    y = fmaf(a4, W1[256 + lane], y);
    x1[(size_t)row * 64 + lane] = fmaxf(y, 0.f);
}

// Layers 2/3: pull spmm on [N,64] (wave per row, lane=dim, 256B coalesced
// gathers) fused with 64x64 Linear (W preloaded in LDS) + ReLU.
__global__ __launch_bounds__(256) void layer23_k(
    const int* __restrict__ rp, const int2* __restrict__ epack,
    const float* __restrict__ xin, const float* __restrict__ W,
    const float* __restrict__ b, float* __restrict__ xout, int n) {
    __shared__ float Ws[64 * 64];
    __shared__ float ts[4][64];
    int tx = threadIdx.x, lane = tx & 63, wid = tx >> 6;
    for (int i = tx; i < 4096; i += 256) Ws[i] = W[i];
    __syncthreads();
    float bias = b[lane];
#pragma unroll
    for (int it = 0; it < 4; ++it) {
        int row = blockIdx.x * 16 + it * 4 + wid;
        float t = 0.f;
        if (row < n) {
            int s = rp[row], e = rp[row + 1];
            for (int j = s; j < e; ++j) {
                int2 cv = epack[j];  // wave-uniform broadcast load
                t = fmaf(__int_as_float(cv.y), xin[(size_t)cv.x * 64 + lane], t);
            }
        }
        ts[wid][lane] = t;
        __syncthreads();  // uniform; also orders LDS write->read
        float y = bias;
        const float4* t4 = (const float4*)ts[wid];
#pragma unroll
        for (int k4 = 0; k4 < 16; ++k4) {
            float4 tv = t4[k4];  // wave-uniform broadcast
            int k = k4 * 4;
            y = fmaf(tv.x, Ws[(k + 0) * 64 + lane], y);
            y = fmaf(tv.y, Ws[(k + 1) * 64 + lane], y);
            y = fmaf(tv.z, Ws[(k + 2) * 64 + lane], y);
            y = fmaf(tv.w, Ws[(k + 3) * 64 + lane], y);
        }
        if (row < n) xout[(size_t)row * 64 + lane] = fmaxf(y, 0.f);
        __syncthreads();
    }
}

// Pool: batch is sorted -> run-length accumulate 64 nodes per wave, flush
// with one atomicAdd per segment boundary per lane.
__global__ void pool_k(const float* __restrict__ x1, const float* __restrict__ x2,
                       const float* __restrict__ x3, const int* __restrict__ batch,
                       float* __restrict__ sums, int* __restrict__ cnts, int n) {
    int lane = threadIdx.x & 63;
    int w = (blockIdx.x * blockDim.x + threadIdx.x) >> 6;
    int node0 = w * 64;
    if (node0 >= n) return;
    int cur = batch[node0];
    float acc = 0.f;
    int cnt = 0;
    int end = min(node0 + 64, n);
    for (int nd = node0; nd < end; ++nd) {
        int bg = batch[nd];  // wave-uniform
        if (bg != cur) {
            atomicAdd(&sums[(size_t)cur * 64 + lane], acc);
            if (lane == 0) atomicAdd(&cnts[cur], cnt);
            acc = 0.f;
            cnt = 0;
            cur = bg;
        }
        size_t o = (size_t)nd * 64 + lane;
        acc += x1[o] + x2[o] + x3[o];
        cnt++;
    }
    atomicAdd(&sums[(size_t)cur * 64 + lane], acc);
    if (lane == 0) atomicAdd(&cnts[cur], cnt);
}

// Head: pooled = sums/(3*cnt); out = softmax(pooled @ Wl + bl). Wave per graph.
__global__ void final_k(const float* __restrict__ sums, const int* __restrict__ cnts,
                        const float* __restrict__ Wl, const float* __restrict__ bl,
                        float* __restrict__ out, int G) {
    int lane = threadIdx.x & 63;
    int g = (blockIdx.x * blockDim.x + threadIdx.x) >> 6;
    if (g >= G) return;
    float c = (float)max(cnts[g], 1);
    float s = sums[(size_t)g * 64 + lane] / (3.f * c);
    float y = (lane < 10) ? bl[lane] : -1e30f;
    for (int k = 0; k < 64; ++k) {
        float sk = __shfl(s, k, 64);
        if (lane < 10) y = fmaf(sk, Wl[k * 10 + lane], y);
    }
    float m = y;
#pragma unroll
    for (int off = 8; off; off >>= 1) m = fmaxf(m, __shfl_xor(m, off, 16));
    float ey = (lane < 10) ? __expf(y - m) : 0.f;
    float sm = ey;
#pragma unroll
    for (int off = 8; off; off >>= 1) sm += __shfl_xor(sm, off, 16);
    if (lane < 10) out[(size_t)g * 10 + lane] = ey / sm;
}

extern "C" void kernel_launch(void* const* d_in, const int* in_sizes, int n_in,
                              void* d_out, int out_size, void* d_ws, size_t ws_size,
                              hipStream_t stream) {
    const float* x = (const float*)d_in[0];
    const int* rows = (const int*)d_in[1];
    const int* cols = (const int*)d_in[2];
    const float* vals = (const float*)d_in[3];
    const int* batch = (const int*)d_in[4];
    const float* W1 = (const float*)d_in[5];
    const float* b1 = (const float*)d_in[6];
    const float* W2 = (const float*)d_in[7];
    const float* b2 = (const float*)d_in[8];
    const float* W3 = (const float*)d_in[9];
    const float* b3 = (const float*)d_in[10];
    const float* Wl = (const float*)d_in[11];
    const float* bl = (const float*)d_in[12];
    float* out = (float*)d_out;

    const int N = in_sizes[4];   // batch array length = n_nodes
    const int E = in_sizes[1];   // rows length = n_edges
    const int G = out_size / 10; // n_graphs

    // Workspace carve-out (~104 MB total)
    char* p = (char*)d_ws;
    size_t off = 0;
    auto alloc = [&](size_t bytes) -> void* {
        off = (off + 255) & ~(size_t)255;
        void* r = (void*)(p + off);
        off += bytes;
        return r;
    };
    int* rp = (int*)alloc((size_t)(N + 1) * 4);
    int* cursor = (int*)alloc((size_t)N * 4);  // doubles as degree array
    int* bsum = (int*)alloc(4096);
    int2* epack = (int2*)alloc((size_t)E * 8);
    float* x1 = (float*)alloc((size_t)N * 64 * 4);
    float* x2 = (float*)alloc((size_t)N * 64 * 4);
    float* x3 = (float*)alloc((size_t)N * 64 * 4);
    float* sums = (float*)alloc((size_t)G * 64 * 4);
    int* cnts = (int*)alloc((size_t)G * 4);

    hipMemsetAsync(cursor, 0, (size_t)N * 4, stream);
    hipMemsetAsync(sums, 0, (size_t)G * 64 * 4, stream);
    hipMemsetAsync(cnts, 0, (size_t)G * 4, stream);

    int eb = (E + 255) / 256;
    int nb = (N + 255) / 256;
    hist_k<<<eb, 256, 0, stream>>>(rows, cursor, E);
    scan1_k<<<nb, 256, 0, stream>>>(cursor, rp, bsum, N);
    scan2_k<<<1, 512, 0, stream>>>(bsum, nb);
    scan3_k<<<nb, 256, 0, stream>>>(bsum, rp, cursor, N, E);
    scatter_k<<<eb, 256, 0, stream>>>(rows, cols, vals, cursor, epack, E);

    layer1_k<<<(N + 3) / 4, 256, 0, stream>>>(rp, epack, x, W1, b1, x1, N);
    layer23_k<<<(N + 15) / 16, 256, 0, stream>>>(rp, epack, x1, W2, b2, x2, N);
    layer23_k<<<(N + 15) / 16, 256, 0, stream>>>(rp, epack, x2, W3, b3, x3, N);

    int pw = (N + 63) / 64;  // waves for pooling
    pool_k<<<(pw + 3) / 4, 256, 0, stream>>>(x1, x2, x3, batch, sums, cnts, N);
    final_k<<<(G + 3) / 4, 256, 0, stream>>>(sums, cnts, Wl, bl, out, G);
}

// Round 2
// 1011.192 us; speedup vs baseline: 1.2705x; 1.2705x over previous
//
#include <hip/hip_runtime.h>

// GCN3: 3x (COO spmm -> Linear(64) -> ReLU), segment-mean pool, softmax head.
// Key algebraic move: relu(spmm(X)@W + b) == relu(spmm(X@W) + b), so each
// layer is a cheap dense transform Z = X@W followed by a pull-spmm with a
// trivial bias+relu epilogue. CSR built per launch (hist/scan/scatter).

__global__ void hist_k(const int* __restrict__ rows, int* __restrict__ deg, int E) {
    int e = blockIdx.x * blockDim.x + threadIdx.x;
    if (e < E) atomicAdd(&deg[rows[e]], 1);
}

__global__ void scan1_k(const int* __restrict__ deg, int* __restrict__ rp,
                        int* __restrict__ bsum, int n) {
    __shared__ int s[256];
    int tx = threadIdx.x;
    int i = blockIdx.x * 256 + tx;
    int v = (i < n) ? deg[i] : 0;
    s[tx] = v;
    __syncthreads();
    for (int off = 1; off < 256; off <<= 1) {
        int t = (tx >= off) ? s[tx - off] : 0;
        __syncthreads();
        s[tx] += t;
        __syncthreads();
    }
    if (i < n) rp[i] = s[tx] - v;  // exclusive
    if (tx == 255) bsum[blockIdx.x] = s[255];
}

__global__ void scan2_k(int* bsum, int nb) {
    __shared__ int s[512];
    int tx = threadIdx.x;
    int v = (tx < nb) ? bsum[tx] : 0;
    s[tx] = v;
    __syncthreads();
    for (int off = 1; off < 512; off <<= 1) {
        int t = (tx >= off) ? s[tx - off] : 0;
        __syncthreads();
        s[tx] += t;
        __syncthreads();
    }
    if (tx < nb) bsum[tx] = s[tx] - v;  // exclusive
}

__global__ void scan3_k(const int* __restrict__ bsum, int* __restrict__ rp,
                        int* __restrict__ cursor, int n, int E) {
    int i = blockIdx.x * 256 + threadIdx.x;
    if (i < n) {
        int v = rp[i] + bsum[blockIdx.x];
        rp[i] = v;
        cursor[i] = v;
    }
    if (i == 0) rp[n] = E;
}

__global__ void scatter_k(const int* __restrict__ rows, const int* __restrict__ cols,
                          const float* __restrict__ vals, int* __restrict__ cursor,
                          int2* __restrict__ epack, int E) {
    int e = blockIdx.x * blockDim.x + threadIdx.x;
    if (e < E) {
        int r = rows[e];
        int p = atomicAdd(&cursor[r], 1);
        epack[p] = make_int2(cols[e], __float_as_int(vals[e]));
    }
}

// Z0 = X @ W1, X:[n,5], W1:[5,64]. Wave per row, lane = out dim.
__global__ __launch_bounds__(256) void dense5_k(
    const float* __restrict__ X, const float* __restrict__ W,
    float* __restrict__ Z, int n) {
    int lane = threadIdx.x & 63;
    int row = (blockIdx.x * blockDim.x + threadIdx.x) >> 6;
    if (row >= n) return;
    float w0 = W[lane], w1 = W[64 + lane], w2 = W[128 + lane],
          w3 = W[192 + lane], w4 = W[256 + lane];
    float xv = (lane < 5) ? X[(size_t)row * 5 + lane] : 0.f;
    float y = __shfl(xv, 0, 64) * w0;
    y = fmaf(__shfl(xv, 1, 64), w1, y);
    y = fmaf(__shfl(xv, 2, 64), w2, y);
    y = fmaf(__shfl(xv, 3, 64), w3, y);
    y = fmaf(__shfl(xv, 4, 64), w4, y);
    Z[(size_t)row * 64 + lane] = y;
}

// Z = X @ W, X:[n,64], W:[64,64] in LDS. Wave per row, lane = out dim.
// X row read via wave-uniform float4 broadcast loads (L1-resident).
__global__ __launch_bounds__(256) void dense64_k(
    const float* __restrict__ X, const float* __restrict__ W,
    float* __restrict__ Z, int n) {
    __shared__ float Ws[64 * 64];
    int tx = threadIdx.x, lane = tx & 63;
    for (int i = tx; i < 4096; i += 256) Ws[i] = W[i];
    __syncthreads();
    int row = (blockIdx.x * blockDim.x + tx) >> 6;
    if (row >= n) return;
    const float4* xr = (const float4*)(X + (size_t)row * 64);
    float y = 0.f;
#pragma unroll
    for (int k4 = 0; k4 < 16; ++k4) {
        float4 xv = xr[k4];  // wave-uniform -> single-line broadcast
        int k = k4 * 4;
        y = fmaf(xv.x, Ws[(k + 0) * 64 + lane], y);
        y = fmaf(xv.y, Ws[(k + 1) * 64 + lane], y);
        y = fmaf(xv.z, Ws[(k + 2) * 64 + lane], y);
        y = fmaf(xv.w, Ws[(k + 3) * 64 + lane], y);
    }
    Z[(size_t)row * 64 + lane] = y;
}

// xout[row] = relu(sum_e v_e * Z[col_e] + b). Wave per row, lane = dim.
// Edge loop unrolled x8 with independent accumulators for memory-level
// parallelism (the round-1 version was a serial 1-deep latency chain).
__global__ __launch_bounds__(256) void spmm_relu_k(
    const int* __restrict__ rp, const int2* __restrict__ epack,
    const float* __restrict__ Z, const float* __restrict__ b,
    float* __restrict__ xout, int n) {
    int lane = threadIdx.x & 63;
    int row = (blockIdx.x * blockDim.x + threadIdx.x) >> 6;
    if (row >= n) return;
    int s = rp[row], e = rp[row + 1];
    float t0 = 0.f, t1 = 0.f, t2 = 0.f, t3 = 0.f,
          t4 = 0.f, t5 = 0.f, t6 = 0.f, t7 = 0.f;
    int j = s;
    for (; j + 8 <= e; j += 8) {
        int2 c0 = epack[j + 0], c1 = epack[j + 1], c2 = epack[j + 2],
             c3 = epack[j + 3], c4 = epack[j + 4], c5 = epack[j + 5],
             c6 = epack[j + 6], c7 = epack[j + 7];
        t0 = fmaf(__int_as_float(c0.y), Z[(size_t)c0.x * 64 + lane], t0);
        t1 = fmaf(__int_as_float(c1.y), Z[(size_t)c1.x * 64 + lane], t1);
        t2 = fmaf(__int_as_float(c2.y), Z[(size_t)c2.x * 64 + lane], t2);
        t3 = fmaf(__int_as_float(c3.y), Z[(size_t)c3.x * 64 + lane], t3);
        t4 = fmaf(__int_as_float(c4.y), Z[(size_t)c4.x * 64 + lane], t4);
        t5 = fmaf(__int_as_float(c5.y), Z[(size_t)c5.x * 64 + lane], t5);
        t6 = fmaf(__int_as_float(c6.y), Z[(size_t)c6.x * 64 + lane], t6);
        t7 = fmaf(__int_as_float(c7.y), Z[(size_t)c7.x * 64 + lane], t7);
    }
    for (; j < e; ++j) {
        int2 cv = epack[j];
        t0 = fmaf(__int_as_float(cv.y), Z[(size_t)cv.x * 64 + lane], t0);
    }
    float t = ((t0 + t1) + (t2 + t3)) + ((t4 + t5) + (t6 + t7));
    xout[(size_t)row * 64 + lane] = fmaxf(t + b[lane], 0.f);
}

// Pool: batch sorted -> run-length accumulate 64 nodes per wave, one
// atomicAdd per segment boundary per lane.
__global__ void pool_k(const float* __restrict__ x1, const float* __restrict__ x2,
                       const float* __restrict__ x3, const int* __restrict__ batch,
                       float* __restrict__ sums, int* __restrict__ cnts, int n) {
    int lane = threadIdx.x & 63;
    int w = (blockIdx.x * blockDim.x + threadIdx.x) >> 6;
    int node0 = w * 64;
    if (node0 >= n) return;
    int cur = batch[node0];
    float acc = 0.f;
    int cnt = 0;
    int end = min(node0 + 64, n);
    for (int nd = node0; nd < end; ++nd) {
        int bg = batch[nd];  // wave-uniform
        if (bg != cur) {
            atomicAdd(&sums[(size_t)cur * 64 + lane], acc);
            if (lane == 0) atomicAdd(&cnts[cur], cnt);
            acc = 0.f;
            cnt = 0;
            cur = bg;
        }
        size_t o = (size_t)nd * 64 + lane;
        acc += x1[o] + x2[o] + x3[o];
        cnt++;
    }
    atomicAdd(&sums[(size_t)cur * 64 + lane], acc);
    if (lane == 0) atomicAdd(&cnts[cur], cnt);
}

// Head: pooled = sums/(3*cnt); out = softmax(pooled @ Wl + bl). Wave per graph.
__global__ void final_k(const float* __restrict__ sums, const int* __restrict__ cnts,
                        const float* __restrict__ Wl, const float* __restrict__ bl,
                        float* __restrict__ out, int G) {
    int lane = threadIdx.x & 63;
    int g = (blockIdx.x * blockDim.x + threadIdx.x) >> 6;
    if (g >= G) return;
    float c = (float)max(cnts[g], 1);
    float s = sums[(size_t)g * 64 + lane] / (3.f * c);
    float y = (lane < 10) ? bl[lane] : -1e30f;
    for (int k = 0; k < 64; ++k) {
        float sk = __shfl(s, k, 64);
        if (lane < 10) y = fmaf(sk, Wl[k * 10 + lane], y);
    }
    float m = y;
#pragma unroll
    for (int off = 8; off; off >>= 1) m = fmaxf(m, __shfl_xor(m, off, 16));
    float ey = (lane < 10) ? __expf(y - m) : 0.f;
    float sm = ey;
#pragma unroll
    for (int off = 8; off; off >>= 1) sm += __shfl_xor(sm, off, 16);
    if (lane < 10) out[(size_t)g * 10 + lane] = ey / sm;
}

extern "C" void kernel_launch(void* const* d_in, const int* in_sizes, int n_in,
                              void* d_out, int out_size, void* d_ws, size_t ws_size,
                              hipStream_t stream) {
    const float* x = (const float*)d_in[0];
    const int* rows = (const int*)d_in[1];
    const int* cols = (const int*)d_in[2];
    const float* vals = (const float*)d_in[3];
    const int* batch = (const int*)d_in[4];
    const float* W1 = (const float*)d_in[5];
    const float* b1 = (const float*)d_in[6];
    const float* W2 = (const float*)d_in[7];
    const float* b2 = (const float*)d_in[8];
    const float* W3 = (const float*)d_in[9];
    const float* b3 = (const float*)d_in[10];
    const float* Wl = (const float*)d_in[11];
    const float* bl = (const float*)d_in[12];
    float* out = (float*)d_out;

    const int N = in_sizes[4];   // batch array length = n_nodes
    const int E = in_sizes[1];   // rows length = n_edges
    const int G = out_size / 10; // n_graphs

    // Workspace carve-out (~130 MB total)
    char* p = (char*)d_ws;
    size_t off = 0;
    auto alloc = [&](size_t bytes) -> void* {
        off = (off + 255) & ~(size_t)255;
        void* r = (void*)(p + off);
        off += bytes;
        return r;
    };
    int* rp = (int*)alloc((size_t)(N + 1) * 4);
    int* cursor = (int*)alloc((size_t)N * 4);  // doubles as degree array
    int* bsum = (int*)alloc(4096);
    int2* epack = (int2*)alloc((size_t)E * 8);
    float* x1 = (float*)alloc((size_t)N * 64 * 4);
    float* x2 = (float*)alloc((size_t)N * 64 * 4);
    float* x3 = (float*)alloc((size_t)N * 64 * 4);
    float* Z = (float*)alloc((size_t)N * 64 * 4);  // reused by all 3 layers
    float* sums = (float*)alloc((size_t)G * 64 * 4);
    int* cnts = (int*)alloc((size_t)G * 4);

    hipMemsetAsync(cursor, 0, (size_t)N * 4, stream);
    hipMemsetAsync(sums, 0, (size_t)G * 64 * 4, stream);
    hipMemsetAsync(cnts, 0, (size_t)G * 4, stream);

    int eb = (E + 255) / 256;
    int nb = (N + 255) / 256;
    hist_k<<<eb, 256, 0, stream>>>(rows, cursor, E);
    scan1_k<<<nb, 256, 0, stream>>>(cursor, rp, bsum, N);
    scan2_k<<<1, 512, 0, stream>>>(bsum, nb);
    scan3_k<<<nb, 256, 0, stream>>>(bsum, rp, cursor, N, E);
    scatter_k<<<eb, 256, 0, stream>>>(rows, cols, vals, cursor, epack, E);

    int rb = (N + 3) / 4;  // wave-per-row blocks
    dense5_k<<<rb, 256, 0, stream>>>(x, W1, Z, N);
    spmm_relu_k<<<rb, 256, 0, stream>>>(rp, epack, Z, b1, x1, N);
    dense64_k<<<rb, 256, 0, stream>>>(x1, W2, Z, N);
    spmm_relu_k<<<rb, 256, 0, stream>>>(rp, epack, Z, b2, x2, N);
    dense64_k<<<rb, 256, 0, stream>>>(x2, W3, Z, N);
    spmm_relu_k<<<rb, 256, 0, stream>>>(rp, epack, Z, b3, x3, N);

    int pw = (N + 63) / 64;  // waves for pooling
    pool_k<<<(pw + 3) / 4, 256, 0, stream>>>(x1, x2, x3, batch, sums, cnts, N);
    final_k<<<(G + 3) / 4, 256, 0, stream>>>(sums, cnts, Wl, bl, out, G);
}